// Round 1
// baseline (840.118 us; speedup 1.0000x reference)
//
#include <hip/hip_runtime.h>
#include <math.h>
#include <stdint.h>

// FrequencyAttention: B=8, L=4096, D=1024, H=16, dh=64, F=2049 (pad 2176), k=64
// Strategy: rfft(X) once; all projections commute with FFT; energy top-k via
// fp16 MFMA GEMM; sparse per-head attention; closed-form sparse irfft; out GEMM.

typedef _Float16 f16;
typedef _Float16 f16x8 __attribute__((ext_vector_type(8)));
typedef float f32x4 __attribute__((ext_vector_type(4)));

#define PI_F 3.14159265358979323846f

__device__ __forceinline__ void gl_lds16(const void* g, void* l) {
  __builtin_amdgcn_global_load_lds((const __attribute__((address_space(1))) void*)g,
                                   (__attribute__((address_space(3))) void*)l, 16, 0, 0);
}

// ---------- prep: transpose Wq, Wo to fp16 [out][in] for MFMA B-operand ----------
__global__ __launch_bounds__(256) void k_prep(const float* __restrict__ Wq, const float* __restrict__ Wo,
                                              f16* __restrict__ WqT, f16* __restrict__ WoT) {
  __shared__ float t[32][33];
  const float* src = blockIdx.z ? Wo : Wq;
  f16* dst = blockIdx.z ? WoT : WqT;
  int c0 = blockIdx.x * 32, r0 = blockIdx.y * 32;
  int tx = threadIdx.x, ty = threadIdx.y;
#pragma unroll
  for (int yy = 0; yy < 4; ++yy)
    t[ty + yy * 8][tx] = src[(size_t)(r0 + ty + yy * 8) * 1024 + c0 + tx];
  __syncthreads();
#pragma unroll
  for (int yy = 0; yy < 4; ++yy)
    dst[(size_t)(c0 + ty + yy * 8) * 1024 + r0 + tx] = (f16)t[tx][ty + yy * 8];
}

// ---------- transpose X (B,L,D) -> Xt (B,D,L) f32 ----------
__global__ __launch_bounds__(256) void k_t1(const float* __restrict__ X, float* __restrict__ Xt) {
  __shared__ float t[32][33];
  int b = blockIdx.z;
  int l0 = blockIdx.x * 32, d0 = blockIdx.y * 32;
  int tx = threadIdx.x, ty = threadIdx.y;
#pragma unroll
  for (int yy = 0; yy < 4; ++yy)
    t[ty + yy * 8][tx] = X[((size_t)b * 4096 + l0 + ty + yy * 8) * 1024 + d0 + tx];
  __syncthreads();
#pragma unroll
  for (int yy = 0; yy < 4; ++yy)
    Xt[((size_t)b * 1024 + d0 + ty + yy * 8) * 4096 + l0 + tx] = t[tx][ty + yy * 8];
}

// ---------- rfft(4096 real) per (b,dm) via 2048-pt complex Stockham + untangle ----------
__global__ __launch_bounds__(256) void k_fft(const float* __restrict__ Xt,
                                             f16* __restrict__ PReU, f16* __restrict__ PImU,
                                             float* __restrict__ sumXf) {
  __shared__ float ar[2048], ai[2048], br[2048], bi[2048];
  __shared__ float twr[1024], twi[1024];
  __shared__ float redr[256], redi[256];
  int tid = threadIdx.x;
  int blk = blockIdx.x;  // b*1024 + dm

  for (int k = tid; k < 1024; k += 256) {
    float ang = (float)k * (-6.28318530717958647692f / 2048.0f);
    twr[k] = cosf(ang);
    twi[k] = sinf(ang);  // e^{-2pi i k/2048}
  }
  const float4* src = (const float4*)(Xt + (size_t)blk * 4096);
#pragma unroll
  for (int r = 0; r < 4; ++r) {
    int i4 = r * 256 + tid;
    float4 v = src[i4];
    ar[2 * i4] = v.x; ai[2 * i4] = v.y;       // z[n] = x[2n] + i x[2n+1]
    ar[2 * i4 + 1] = v.z; ai[2 * i4 + 1] = v.w;
  }
  __syncthreads();
  float *cr = ar, *ci = ai, *nr = br, *ni = bi;
  for (int st = 0; st < 11; ++st) {
#pragma unroll
    for (int r = 0; r < 4; ++r) {
      int i = r * 256 + tid;           // butterfly index 0..1023
      int p = i >> st;
      int q = i & ((1 << st) - 1);
      float xr = cr[i], xi = ci[i];
      float yr = cr[i + 1024], yi = ci[i + 1024];
      float sr = xr - yr, si = xi - yi;
      int tix = p << st;               // p * (2048/ncur)
      float wr = twr[tix], wi = twi[tix];
      int o0 = q + (p << (st + 1));
      nr[o0] = xr + yr; ni[o0] = xi + yi;
      nr[o0 + (1 << st)] = sr * wr - si * wi;
      ni[o0 + (1 << st)] = sr * wi + si * wr;
    }
    __syncthreads();
    float* tp;
    tp = cr; cr = nr; nr = tp;
    tp = ci; ci = ni; ni = tp;
  }
  // untangle real FFT: X[f] = E + e^{-2pi i f/4096} * O, f = 0..2048
  float sumr = 0.f, sumi = 0.f;
  const float c2 = 6.28318530717958647692f / 4096.0f;
  size_t obase = (size_t)blk * 2049;
  for (int f = tid; f <= 2048; f += 256) {
    int fz = f & 2047, fm = (2048 - f) & 2047;
    float zr = cr[fz], zi = ci[fz], mr = cr[fm], mi = ci[fm];
    float Er = 0.5f * (zr + mr), Ei = 0.5f * (zi - mi);
    float Or = 0.5f * (zi + mi), Oi = -0.5f * (zr - mr);
    float a = c2 * (float)f;
    float wr = cosf(a), wi = -sinf(a);
    float Xr = Er + wr * Or - wi * Oi;
    float Xi = Ei + wr * Oi + wi * Or;
    PReU[obase + f] = (f16)Xr;
    PImU[obase + f] = (f16)Xi;
    sumr += Xr; sumi += Xi;
  }
  __syncthreads();
  redr[tid] = sumr; redi[tid] = sumi;
  __syncthreads();
  for (int s = 128; s > 0; s >>= 1) {
    if (tid < s) { redr[tid] += redr[tid + s]; redi[tid] += redi[tid + s]; }
    __syncthreads();
  }
  if (tid == 0) { sumXf[2 * blk] = redr[0]; sumXf[2 * blk + 1] = redi[0]; }
}

// ---------- C = mean_f(q_freq) = (sumXf @ Wq + L*bq) / F ----------
__global__ __launch_bounds__(256) void k_C(const float* __restrict__ sumXf, const float* __restrict__ Wq,
                                           const float* __restrict__ bq,
                                           float* __restrict__ Cre, float* __restrict__ Cim) {
  int b = blockIdx.x >> 2;
  int hd = ((blockIdx.x & 3) << 8) + threadIdx.x;
  float accr = 0.f, acci = 0.f;
  for (int dm = 0; dm < 1024; ++dm) {
    float w = Wq[(size_t)dm * 1024 + hd];
    accr += sumXf[2 * (b * 1024 + dm)] * w;
    acci += sumXf[2 * (b * 1024 + dm) + 1] * w;
  }
  Cre[b * 1024 + hd] = (accr + 4096.0f * bq[hd]) * (1.0f / 2049.0f);
  Cim[b * 1024 + hd] = acci * (1.0f / 2049.0f);
}

// ---------- transpose planes (B*D, 2049) -> (B, 2176, D) fp16, zero-pad ----------
__global__ __launch_bounds__(256) void k_t2(const f16* __restrict__ PReU, const f16* __restrict__ PImU,
                                            f16* __restrict__ PReT, f16* __restrict__ PImT) {
  __shared__ f16 t[32][33];
  int z = blockIdx.z;
  int b = z >> 1;
  const f16* src = (z & 1) ? PImU : PReU;
  f16* dst = (z & 1) ? PImT : PReT;
  int f0 = blockIdx.x * 32, d0 = blockIdx.y * 32;
  int tx = threadIdx.x, ty = threadIdx.y;
#pragma unroll
  for (int yy = 0; yy < 4; ++yy) {
    int ff = f0 + tx;
    t[ty + yy * 8][tx] = (ff < 2049) ? src[(size_t)(b * 1024 + d0 + ty + yy * 8) * 2049 + ff] : (f16)0.f;
  }
  __syncthreads();
#pragma unroll
  for (int yy = 0; yy < 4; ++yy)
    dst[((size_t)b * 2176 + f0 + ty + yy * 8) * 1024 + d0 + tx] = t[tx][ty + yy * 8];
}

// ---------- energy GEMM: |Xf @ Wq| head-mean, fp16 MFMA, BM=128 BN=64 BK=64 ----------
__global__ __launch_bounds__(256) void k_energy(const f16* __restrict__ PReT, const f16* __restrict__ PImT,
                                                const f16* __restrict__ WqT, const float* __restrict__ bq,
                                                float* __restrict__ energy) {
  __shared__ __align__(16) f16 sAre[128 * 64];
  __shared__ __align__(16) f16 sAim[128 * 64];
  __shared__ __align__(16) f16 sBT[64 * 64];
  int tid = threadIdx.x;
  int lane = tid & 63, wv = tid >> 6;
  int bN = blockIdx.x;    // head
  int Mblk = blockIdx.y;  // 136 tiles of 128 rows over (b, f_pad)
  f32x4 accRe[2][4], accIm[2][4];
#pragma unroll
  for (int mf = 0; mf < 2; ++mf)
#pragma unroll
    for (int nf = 0; nf < 4; ++nf) { accRe[mf][nf] = 0; accIm[mf][nf] = 0; }

  const char* gAre0 = (const char*)PReT + (size_t)(Mblk * 128) * 2048;
  const char* gAim0 = (const char*)PImT + (size_t)(Mblk * 128) * 2048;
  const char* gB0 = (const char*)WqT + (size_t)(bN * 64) * 2048;
  int rb = wv * 32;

  for (int ks = 0; ks < 16; ++ks) {
    int kb = ks * 128;  // byte offset in row
#pragma unroll
    for (int it = 0; it < 4; ++it) {
      int bo_ = it * 4096 + tid * 16;
      int row = bo_ >> 7, cb = bo_ & 127;
      gl_lds16(gAre0 + (size_t)row * 2048 + kb + cb, (char*)sAre + it * 4096 + (tid >> 6) * 1024);
    }
#pragma unroll
    for (int it = 0; it < 4; ++it) {
      int bo_ = it * 4096 + tid * 16;
      int row = bo_ >> 7, cb = bo_ & 127;
      gl_lds16(gAim0 + (size_t)row * 2048 + kb + cb, (char*)sAim + it * 4096 + (tid >> 6) * 1024);
    }
#pragma unroll
    for (int it = 0; it < 2; ++it) {
      int bo_ = it * 4096 + tid * 16;
      int row = bo_ >> 7, cb = bo_ & 127;
      gl_lds16(gB0 + (size_t)row * 2048 + kb + cb, (char*)sBT + it * 4096 + (tid >> 6) * 1024);
    }
    __syncthreads();
#pragma unroll
    for (int kk = 0; kk < 64; kk += 32) {
      int ko = kk + ((lane >> 4) << 3);
      f16x8 aRe[2], aIm[2], bF[4];
#pragma unroll
      for (int mf = 0; mf < 2; ++mf) {
        aRe[mf] = *(const f16x8*)&sAre[(rb + mf * 16 + (lane & 15)) * 64 + ko];
        aIm[mf] = *(const f16x8*)&sAim[(rb + mf * 16 + (lane & 15)) * 64 + ko];
      }
#pragma unroll
      for (int nf = 0; nf < 4; ++nf)
        bF[nf] = *(const f16x8*)&sBT[(nf * 16 + (lane & 15)) * 64 + ko];
#pragma unroll
      for (int mf = 0; mf < 2; ++mf)
#pragma unroll
        for (int nf = 0; nf < 4; ++nf) {
          accRe[mf][nf] = __builtin_amdgcn_mfma_f32_16x16x32_f16(aRe[mf], bF[nf], accRe[mf][nf], 0, 0, 0);
          accIm[mf][nf] = __builtin_amdgcn_mfma_f32_16x16x32_f16(aIm[mf], bF[nf], accIm[mf][nf], 0, 0, 0);
        }
    }
    __syncthreads();
  }
  // epilogue: bias at f==0, |z|, mean over 64 head dims
#pragma unroll
  for (int mf = 0; mf < 2; ++mf) {
#pragma unroll
    for (int r = 0; r < 4; ++r) {
      int grow = Mblk * 128 + rb + mf * 16 + ((lane >> 4) << 2) + r;
      int bb = grow / 2176;
      int fp = grow - bb * 2176;
      float s = 0.f;
#pragma unroll
      for (int nf = 0; nf < 4; ++nf) {
        float re = accRe[mf][nf][r];
        float im = accIm[mf][nf][r];
        if (fp == 0) re += 4096.0f * bq[bN * 64 + nf * 16 + (lane & 15)];
        s += sqrtf(re * re + im * im);
      }
#pragma unroll
      for (int off = 1; off < 16; off <<= 1) s += __shfl_xor(s, off);
      if ((lane & 15) == 0)
        energy[((size_t)bb * 16 + bN) * 2176 + fp] = s * 0.015625f;
    }
  }
}

// ---------- top-64 per (b,h), descending, ties -> lower index ----------
__global__ __launch_bounds__(256) void k_topk(const float* __restrict__ energy, int* __restrict__ idxb) {
  __shared__ float vals[2049];
  __shared__ unsigned long long wbest[4];
  int tid = threadIdx.x, bh = blockIdx.x;
  const float* e = energy + (size_t)bh * 2176;
  for (int i = tid; i < 2049; i += 256) vals[i] = e[i];
  __syncthreads();
  for (int it = 0; it < 64; ++it) {
    unsigned long long best = 0ull;
    for (int f = tid; f < 2049; f += 256) {
      unsigned b32 = __float_as_uint(vals[f]);
      b32 = (b32 & 0x80000000u) ? ~b32 : (b32 | 0x80000000u);  // order-preserving
      unsigned long long k = ((unsigned long long)b32 << 12) | (unsigned)(4095 - f);
      best = (k > best) ? k : best;
    }
#pragma unroll
    for (int off = 32; off > 0; off >>= 1) {
      unsigned long long o = __shfl_xor(best, off);
      best = (o > best) ? o : best;
    }
    if ((tid & 63) == 0) wbest[tid >> 6] = best;
    __syncthreads();
    if (tid == 0) {
      unsigned long long b0 = wbest[0] > wbest[1] ? wbest[0] : wbest[1];
      unsigned long long b1 = wbest[2] > wbest[3] ? wbest[2] : wbest[3];
      unsigned long long bb = b0 > b1 ? b0 : b1;
      int f = 4095 - (int)(bb & 4095ull);
      idxb[bh * 64 + it] = f;
      vals[f] = -1.0f;
    }
    __syncthreads();
  }
}

// ---------- per (b,h): q/k/v at 64 bins, softmax, amp = w*(attn*v - C_re) ----------
__global__ __launch_bounds__(1024) void k_attn(const f16* __restrict__ PReT, const int* __restrict__ idxb,
                                               const float* __restrict__ Wq, const float* __restrict__ Wk,
                                               const float* __restrict__ Wv, const float* __restrict__ bq,
                                               const float* __restrict__ bk, const float* __restrict__ bv,
                                               const float* __restrict__ Cre, float* __restrict__ amp) {
  __shared__ float sA[64][33];
  __shared__ __align__(16) float sWq[32][64];
  __shared__ __align__(16) float sWk[32][64];
  __shared__ __align__(16) float sWv[32][64];
  __shared__ float scores[64], attns[64];
  __shared__ int fjs[64];
  int tid = threadIdx.x, bh = blockIdx.x;
  int b = bh >> 4, h = bh & 15;
  if (tid < 64) fjs[tid] = idxb[bh * 64 + tid];
  __syncthreads();
  int j = tid >> 4, dq = tid & 15;
  float q0 = 0, q1 = 0, q2 = 0, q3 = 0;
  float k0v = 0, k1 = 0, k2 = 0, k3 = 0;
  float v0 = 0, v1 = 0, v2 = 0, v3 = 0;
  for (int ks = 0; ks < 32; ++ks) {
    int kb = ks * 32;
    __syncthreads();
    for (int e = tid; e < 2048; e += 1024) {
      int jr = e >> 5, kk = e & 31;
      sA[jr][kk] = (float)PReT[(size_t)(b * 2176 + fjs[jr]) * 1024 + kb + kk];
    }
    for (int e = tid; e < 2048; e += 1024) {
      int kk = e >> 6, c = e & 63;
      size_t gi = (size_t)(kb + kk) * 1024 + h * 64 + c;
      sWq[kk][c] = Wq[gi]; sWk[kk][c] = Wk[gi]; sWv[kk][c] = Wv[gi];
    }
    __syncthreads();
#pragma unroll 8
    for (int kk = 0; kk < 32; ++kk) {
      float a = sA[j][kk];
      float4 wq = *(const float4*)&sWq[kk][dq * 4];
      float4 wk = *(const float4*)&sWk[kk][dq * 4];
      float4 wv = *(const float4*)&sWv[kk][dq * 4];
      q0 = fmaf(a, wq.x, q0); q1 = fmaf(a, wq.y, q1); q2 = fmaf(a, wq.z, q2); q3 = fmaf(a, wq.w, q3);
      k0v = fmaf(a, wk.x, k0v); k1 = fmaf(a, wk.y, k1); k2 = fmaf(a, wk.z, k2); k3 = fmaf(a, wk.w, k3);
      v0 = fmaf(a, wv.x, v0); v1 = fmaf(a, wv.y, v1); v2 = fmaf(a, wv.z, v2); v3 = fmaf(a, wv.w, v3);
    }
  }
  int fj = fjs[j];
  if (fj == 0) {  // time-domain bias appears only at DC bin, scaled by L
    float4 b4q = *(const float4*)&bq[h * 64 + dq * 4];
    float4 b4k = *(const float4*)&bk[h * 64 + dq * 4];
    float4 b4v = *(const float4*)&bv[h * 64 + dq * 4];
    q0 += 4096.f * b4q.x; q1 += 4096.f * b4q.y; q2 += 4096.f * b4q.z; q3 += 4096.f * b4q.w;
    k0v += 4096.f * b4k.x; k1 += 4096.f * b4k.y; k2 += 4096.f * b4k.z; k3 += 4096.f * b4k.w;
    v0 += 4096.f * b4v.x; v1 += 4096.f * b4v.y; v2 += 4096.f * b4v.z; v3 += 4096.f * b4v.w;
  }
  float sc = q0 * k0v + q1 * k1 + q2 * k2 + q3 * k3;
#pragma unroll
  for (int off = 1; off < 16; off <<= 1) sc += __shfl_xor(sc, off);
  if (dq == 0) scores[j] = sc * 0.125f;  // / (sqrt(64) + 1e-8) == 0.125f in f32
  __syncthreads();
  if (tid < 64) {
    float s = scores[tid];
    float m = s;
#pragma unroll
    for (int off = 32; off > 0; off >>= 1) m = fmaxf(m, __shfl_xor(m, off));
    float ev = expf(s - m);
    float sm = ev;
#pragma unroll
    for (int off = 32; off > 0; off >>= 1) sm += __shfl_xor(sm, off);
    attns[tid] = ev / sm;
  }
  __syncthreads();
  float at = attns[j];
  float wj = (fj == 0 || fj == 2048) ? 0.5f : 1.0f;  // half-weight DC/Nyquist
  float4 c4 = *(const float4*)&Cre[b * 1024 + h * 64 + dq * 4];
  float4 av;
  av.x = wj * (at * v0 - c4.x); av.y = wj * (at * v1 - c4.y);
  av.z = wj * (at * v2 - c4.z); av.w = wj * (at * v3 - c4.w);
  *(float4*)&amp[((size_t)bh * 64 + j) * 64 + dq * 4] = av;
}

// ---------- sparse irfft: out_t = [t==0]Cre + (2/L)(sum_j amp_j cos + Cim*g(t)) ----------
__global__ __launch_bounds__(256) void k_ot(const float* __restrict__ amp, const int* __restrict__ idxb,
                                            const float* __restrict__ Cre, const float* __restrict__ Cim,
                                            f16* __restrict__ OT) {
  __shared__ __align__(16) float sAmp[64][64];
  __shared__ __align__(16) float sCre[64];
  __shared__ __align__(16) float sCim[64];
  __shared__ int fjs[64];
  int tid = threadIdx.x;
  int bh = blockIdx.x >> 4, tch = blockIdx.x & 15;
  int b = bh >> 4, h = bh & 15;
  for (int e = tid; e < 4096; e += 256) ((float*)sAmp)[e] = amp[(size_t)bh * 4096 + e];
  if (tid < 64) {
    sCre[tid] = Cre[b * 1024 + h * 64 + tid];
    sCim[tid] = Cim[b * 1024 + h * 64 + tid];
    fjs[tid] = idxb[bh * 64 + tid];
  }
  __syncthreads();
  int t = tch * 256 + tid;
  float4 acc[16];
#pragma unroll
  for (int d4 = 0; d4 < 16; ++d4) acc[d4] = make_float4(0.f, 0.f, 0.f, 0.f);
  float ssum = 0.f;
  for (int jj = 0; jj < 64; ++jj) {
    int r = (fjs[jj] * t) & 4095;  // exact angle reduction: (f*t) mod L
    float ang = (float)r * 0.00153398078788564123f;  // 2*pi/4096
    float sn, cs;
    __sincosf(ang, &sn, &cs);
    ssum += sn;
    const float4* arow = (const float4*)&sAmp[jj][0];
#pragma unroll
    for (int d4 = 0; d4 < 16; ++d4) {
      float4 a = arow[d4];
      acc[d4].x = fmaf(a.x, cs, acc[d4].x);
      acc[d4].y = fmaf(a.y, cs, acc[d4].y);
      acc[d4].z = fmaf(a.z, cs, acc[d4].z);
      acc[d4].w = fmaf(a.w, cs, acc[d4].w);
    }
  }
  float g = ssum;
  if (t & 1) {  // constant-spectrum irfft contributes -(2/L)Cim*cot(pi t/L) at odd t
    int tp = (t <= 2048) ? t : 4096 - t;
    float sg = (t <= 2048) ? 1.f : -1.f;
    float aa = (float)tp * (PI_F / 4096.0f);
    g -= sg * (cosf(aa) / sinf(aa));
  }
  const float s2L = 2.0f / 4096.0f;
  int isT0 = (t == 0);
  f16* o16 = OT + ((size_t)bh * 4096 + t) * 64;
#pragma unroll
  for (int d4 = 0; d4 < 16; ++d4) {
    float4 ci4 = *(const float4*)&sCim[d4 * 4];
    float4 cr4 = *(const float4*)&sCre[d4 * 4];
    acc[d4].x = s2L * (acc[d4].x + ci4.x * g) + (isT0 ? cr4.x : 0.f);
    acc[d4].y = s2L * (acc[d4].y + ci4.y * g) + (isT0 ? cr4.y : 0.f);
    acc[d4].z = s2L * (acc[d4].z + ci4.z * g) + (isT0 ? cr4.z : 0.f);
    acc[d4].w = s2L * (acc[d4].w + ci4.w * g) + (isT0 ? cr4.w : 0.f);
  }
#pragma unroll
  for (int p = 0; p < 8; ++p) {
    float4 a = acc[2 * p], bb = acc[2 * p + 1];
    f16x8 v;
    v[0] = (f16)a.x; v[1] = (f16)a.y; v[2] = (f16)a.z; v[3] = (f16)a.w;
    v[4] = (f16)bb.x; v[5] = (f16)bb.y; v[6] = (f16)bb.z; v[7] = (f16)bb.w;
    *(f16x8*)(o16 + p * 8) = v;
  }
}

// ---------- final GEMM: out = OT(B,H,L,d as (b t) x (h d)) @ Wo + bo ----------
__global__ __launch_bounds__(256) void k_final(const f16* __restrict__ OT, const f16* __restrict__ WoT,
                                               const float* __restrict__ bo, float* __restrict__ out) {
  __shared__ __align__(16) f16 sA[128 * 64];
  __shared__ __align__(16) f16 sB[128 * 64];
  int tid = threadIdx.x, lane = tid & 63, wv = tid >> 6;
  int bN = blockIdx.x, Mblk = blockIdx.y;
  int wr = wv >> 1, wc = wv & 1;
  f32x4 acc[4][4];
#pragma unroll
  for (int mf = 0; mf < 4; ++mf)
#pragma unroll
    for (int nf = 0; nf < 4; ++nf) acc[mf][nf] = 0;
  int b = Mblk >> 5, t0 = (Mblk & 31) * 128;
  const char* gB0 = (const char*)WoT + (size_t)(bN * 128) * 2048;
  for (int ks = 0; ks < 16; ++ks) {  // k-step = one head's 64 dims
    const char* gA = (const char*)OT + (size_t)((b * 16 + ks) * 4096 + t0) * 128;
#pragma unroll
    for (int it = 0; it < 4; ++it) {
      int bo_ = it * 4096 + tid * 16;
      gl_lds16(gA + bo_, (char*)sA + it * 4096 + (tid >> 6) * 1024);
    }
    int kb = ks * 128;
#pragma unroll
    for (int it = 0; it < 4; ++it) {
      int bo_ = it * 4096 + tid * 16;
      int row = bo_ >> 7, cb = bo_ & 127;
      gl_lds16(gB0 + (size_t)row * 2048 + kb + cb, (char*)sB + it * 4096 + (tid >> 6) * 1024);
    }
    __syncthreads();
#pragma unroll
    for (int kk = 0; kk < 64; kk += 32) {
      int ko = kk + ((lane >> 4) << 3);
      f16x8 aF[4], bF[4];
#pragma unroll
      for (int mf = 0; mf < 4; ++mf)
        aF[mf] = *(const f16x8*)&sA[(wr * 64 + mf * 16 + (lane & 15)) * 64 + ko];
#pragma unroll
      for (int nf = 0; nf < 4; ++nf)
        bF[nf] = *(const f16x8*)&sB[(wc * 64 + nf * 16 + (lane & 15)) * 64 + ko];
#pragma unroll
      for (int mf = 0; mf < 4; ++mf)
#pragma unroll
        for (int nf = 0; nf < 4; ++nf)
          acc[mf][nf] = __builtin_amdgcn_mfma_f32_16x16x32_f16(aF[mf], bF[nf], acc[mf][nf], 0, 0, 0);
    }
    __syncthreads();
  }
#pragma unroll
  for (int nf = 0; nf < 4; ++nf) {
    int gcol = bN * 128 + wc * 64 + nf * 16 + (lane & 15);
    float bcol = bo[gcol];
#pragma unroll
    for (int mf = 0; mf < 4; ++mf) {
#pragma unroll
      for (int r = 0; r < 4; ++r) {
        int grow = Mblk * 128 + wr * 64 + mf * 16 + ((lane >> 4) << 2) + r;
        out[(size_t)grow * 1024 + gcol] = acc[mf][nf][r] + bcol;
      }
    }
  }
}

extern "C" void kernel_launch(void* const* d_in, const int* in_sizes, int n_in,
                              void* d_out, int out_size, void* d_ws, size_t ws_size,
                              hipStream_t stream) {
  const float* X = (const float*)d_in[0];
  const float* Wq = (const float*)d_in[1];
  const float* bq = (const float*)d_in[2];
  const float* Wk = (const float*)d_in[3];
  const float* bk = (const float*)d_in[4];
  const float* Wv = (const float*)d_in[5];
  const float* bv = (const float*)d_in[6];
  const float* Wo = (const float*)d_in[7];
  const float* bo = (const float*)d_in[8];
  float* out = (float*)d_out;

  if (ws_size < 208928768ULL) return;  // workspace plan below needs ~209MB
  char* w = (char*)d_ws;
  // Region1 (0..134MB): Xt f32 (B,D,L); after FFT reused for transposed fp16 planes
  float* Xt = (float*)(w);
  f16* PReT = (f16*)(w);
  f16* PImT = (f16*)(w + 35651584);
  // Region2 (134..201MB): untransposed fp16 planes; after t2 reused for OT
  char* R2 = w + 134217728;
  f16* PReU = (f16*)(R2);
  f16* PImU = (f16*)(R2 + 33570816);
  f16* OT = (f16*)(R2);
  // Region3: small buffers
  char* R3 = R2 + 67141632;
  float* sumXf = (float*)(R3);
  float* Cre = (float*)(R3 + 65536);
  float* Cim = (float*)(R3 + 98304);
  float* energy = (float*)(R3 + 131072);
  int* idxb = (int*)(R3 + 1245184);
  float* amp = (float*)(R3 + 1277952);
  f16* WqT = (f16*)(R3 + 3375104);
  f16* WoT = (f16*)(R3 + 5472256);

  dim3 b32(32, 8);
  hipLaunchKernelGGL(k_prep, dim3(32, 32, 2), b32, 0, stream, Wq, Wo, WqT, WoT);
  hipLaunchKernelGGL(k_t1, dim3(128, 32, 8), b32, 0, stream, X, Xt);
  hipLaunchKernelGGL(k_fft, dim3(8192), dim3(256), 0, stream, Xt, PReU, PImU, sumXf);
  hipLaunchKernelGGL(k_C, dim3(32), dim3(256), 0, stream, sumXf, Wq, bq, Cre, Cim);
  hipLaunchKernelGGL(k_t2, dim3(68, 32, 16), b32, 0, stream, PReU, PImU, PReT, PImT);
  hipLaunchKernelGGL(k_energy, dim3(16, 136), dim3(256), 0, stream, PReT, PImT, WqT, bq, energy);
  hipLaunchKernelGGL(k_topk, dim3(128), dim3(256), 0, stream, energy, idxb);
  hipLaunchKernelGGL(k_attn, dim3(128), dim3(1024), 0, stream, PReT, idxb, Wq, Wk, Wv, bq, bk, bv, Cre, amp);
  hipLaunchKernelGGL(k_ot, dim3(2048), dim3(256), 0, stream, amp, idxb, Cre, Cim, OT);
  hipLaunchKernelGGL(k_final, dim3(8, 256), dim3(256), 0, stream, OT, WoT, bo, out);
}

// Round 2
// 703.032 us; speedup vs baseline: 1.1950x; 1.1950x over previous
//
#include <hip/hip_runtime.h>
#include <math.h>
#include <stdint.h>

// FrequencyAttention: B=8, L=4096, D=1024, H=16, dh=64, F=2049 (pad 2176), k=64
// Strategy: rfft(X) once; all projections commute with FFT; energy top-k via
// fp16 MFMA GEMM; sparse per-head attention (MFMA, K-split); closed-form
// sparse irfft; out GEMM.

typedef _Float16 f16;
typedef _Float16 f16x8 __attribute__((ext_vector_type(8)));
typedef float f32x4 __attribute__((ext_vector_type(4)));

#define PI_F 3.14159265358979323846f

__device__ __forceinline__ void gl_lds16(const void* g, void* l) {
  __builtin_amdgcn_global_load_lds((const __attribute__((address_space(1))) void*)g,
                                   (__attribute__((address_space(3))) void*)l, 16, 0, 0);
}

// ---------- prep: transpose Wq, Wo to fp16 [out][in] for MFMA B-operand ----------
__global__ __launch_bounds__(256) void k_prep(const float* __restrict__ Wq, const float* __restrict__ Wo,
                                              f16* __restrict__ WqT, f16* __restrict__ WoT) {
  __shared__ float t[32][33];
  const float* src = blockIdx.z ? Wo : Wq;
  f16* dst = blockIdx.z ? WoT : WqT;
  int c0 = blockIdx.x * 32, r0 = blockIdx.y * 32;
  int tx = threadIdx.x, ty = threadIdx.y;
#pragma unroll
  for (int yy = 0; yy < 4; ++yy)
    t[ty + yy * 8][tx] = src[(size_t)(r0 + ty + yy * 8) * 1024 + c0 + tx];
  __syncthreads();
#pragma unroll
  for (int yy = 0; yy < 4; ++yy)
    dst[(size_t)(c0 + ty + yy * 8) * 1024 + r0 + tx] = (f16)t[tx][ty + yy * 8];
}

// ---------- prep2: transpose Wk, Wv to fp16 (runs after k_fft; lives in region1 tail) ----------
__global__ __launch_bounds__(256) void k_prep2(const float* __restrict__ Wk, const float* __restrict__ Wv,
                                               f16* __restrict__ WkT, f16* __restrict__ WvT) {
  __shared__ float t[32][33];
  const float* src = blockIdx.z ? Wv : Wk;
  f16* dst = blockIdx.z ? WvT : WkT;
  int c0 = blockIdx.x * 32, r0 = blockIdx.y * 32;
  int tx = threadIdx.x, ty = threadIdx.y;
#pragma unroll
  for (int yy = 0; yy < 4; ++yy)
    t[ty + yy * 8][tx] = src[(size_t)(r0 + ty + yy * 8) * 1024 + c0 + tx];
  __syncthreads();
#pragma unroll
  for (int yy = 0; yy < 4; ++yy)
    dst[(size_t)(c0 + ty + yy * 8) * 1024 + r0 + tx] = (f16)t[tx][ty + yy * 8];
}

// ---------- transpose X (B,L,D) -> Xt (B,D,L) f32 ----------
__global__ __launch_bounds__(256) void k_t1(const float* __restrict__ X, float* __restrict__ Xt) {
  __shared__ float t[32][33];
  int b = blockIdx.z;
  int l0 = blockIdx.x * 32, d0 = blockIdx.y * 32;
  int tx = threadIdx.x, ty = threadIdx.y;
#pragma unroll
  for (int yy = 0; yy < 4; ++yy)
    t[ty + yy * 8][tx] = X[((size_t)b * 4096 + l0 + ty + yy * 8) * 1024 + d0 + tx];
  __syncthreads();
#pragma unroll
  for (int yy = 0; yy < 4; ++yy)
    Xt[((size_t)b * 1024 + d0 + ty + yy * 8) * 4096 + l0 + tx] = t[tx][ty + yy * 8];
}

// ---------- rfft(4096 real) per (b,dm) via 2048-pt complex Stockham + untangle ----------
__global__ __launch_bounds__(256) void k_fft(const float* __restrict__ Xt,
                                             f16* __restrict__ PReU, f16* __restrict__ PImU,
                                             float* __restrict__ sumXf) {
  __shared__ float ar[2048], ai[2048], br[2048], bi[2048];
  __shared__ float twr[1024], twi[1024];
  __shared__ float redr[256], redi[256];
  int tid = threadIdx.x;
  int blk = blockIdx.x;  // b*1024 + dm

  for (int k = tid; k < 1024; k += 256) {
    float ang = (float)k * (-6.28318530717958647692f / 2048.0f);
    twr[k] = cosf(ang);
    twi[k] = sinf(ang);  // e^{-2pi i k/2048}
  }
  const float4* src = (const float4*)(Xt + (size_t)blk * 4096);
#pragma unroll
  for (int r = 0; r < 4; ++r) {
    int i4 = r * 256 + tid;
    float4 v = src[i4];
    ar[2 * i4] = v.x; ai[2 * i4] = v.y;       // z[n] = x[2n] + i x[2n+1]
    ar[2 * i4 + 1] = v.z; ai[2 * i4 + 1] = v.w;
  }
  __syncthreads();
  float *cr = ar, *ci = ai, *nr = br, *ni = bi;
  for (int st = 0; st < 11; ++st) {
#pragma unroll
    for (int r = 0; r < 4; ++r) {
      int i = r * 256 + tid;           // butterfly index 0..1023
      int p = i >> st;
      int q = i & ((1 << st) - 1);
      float xr = cr[i], xi = ci[i];
      float yr = cr[i + 1024], yi = ci[i + 1024];
      float sr = xr - yr, si = xi - yi;
      int tix = p << st;               // p * (2048/ncur)
      float wr = twr[tix], wi = twi[tix];
      int o0 = q + (p << (st + 1));
      nr[o0] = xr + yr; ni[o0] = xi + yi;
      nr[o0 + (1 << st)] = sr * wr - si * wi;
      ni[o0 + (1 << st)] = sr * wi + si * wr;
    }
    __syncthreads();
    float* tp;
    tp = cr; cr = nr; nr = tp;
    tp = ci; ci = ni; ni = tp;
  }
  // untangle real FFT: X[f] = E + e^{-2pi i f/4096} * O, f = 0..2048
  float sumr = 0.f, sumi = 0.f;
  const float c2 = 6.28318530717958647692f / 4096.0f;
  size_t obase = (size_t)blk * 2049;
  for (int f = tid; f <= 2048; f += 256) {
    int fz = f & 2047, fm = (2048 - f) & 2047;
    float zr = cr[fz], zi = ci[fz], mr = cr[fm], mi = ci[fm];
    float Er = 0.5f * (zr + mr), Ei = 0.5f * (zi - mi);
    float Or = 0.5f * (zi + mi), Oi = -0.5f * (zr - mr);
    float a = c2 * (float)f;
    float wr = cosf(a), wi = -sinf(a);
    float Xr = Er + wr * Or - wi * Oi;
    float Xi = Ei + wr * Oi + wi * Or;
    PReU[obase + f] = (f16)Xr;
    PImU[obase + f] = (f16)Xi;
    sumr += Xr; sumi += Xi;
  }
  __syncthreads();
  redr[tid] = sumr; redi[tid] = sumi;
  __syncthreads();
  for (int s = 128; s > 0; s >>= 1) {
    if (tid < s) { redr[tid] += redr[tid + s]; redi[tid] += redi[tid + s]; }
    __syncthreads();
  }
  if (tid == 0) { sumXf[2 * blk] = redr[0]; sumXf[2 * blk + 1] = redi[0]; }
}

// ---------- C = mean_f(q_freq) = (sumXf @ Wq + L*bq) / F ----------
__global__ __launch_bounds__(256) void k_C(const float* __restrict__ sumXf, const float* __restrict__ Wq,
                                           const float* __restrict__ bq,
                                           float* __restrict__ Cre, float* __restrict__ Cim) {
  int b = blockIdx.x >> 2;
  int hd = ((blockIdx.x & 3) << 8) + threadIdx.x;
  float accr = 0.f, acci = 0.f;
  for (int dm = 0; dm < 1024; ++dm) {
    float w = Wq[(size_t)dm * 1024 + hd];
    accr += sumXf[2 * (b * 1024 + dm)] * w;
    acci += sumXf[2 * (b * 1024 + dm) + 1] * w;
  }
  Cre[b * 1024 + hd] = (accr + 4096.0f * bq[hd]) * (1.0f / 2049.0f);
  Cim[b * 1024 + hd] = acci * (1.0f / 2049.0f);
}

// ---------- transpose planes (B*D, 2049) -> (B, 2176, D) fp16, zero-pad ----------
__global__ __launch_bounds__(256) void k_t2(const f16* __restrict__ PReU, const f16* __restrict__ PImU,
                                            f16* __restrict__ PReT, f16* __restrict__ PImT) {
  __shared__ f16 t[32][33];
  int z = blockIdx.z;
  int b = z >> 1;
  const f16* src = (z & 1) ? PImU : PReU;
  f16* dst = (z & 1) ? PImT : PReT;
  int f0 = blockIdx.x * 32, d0 = blockIdx.y * 32;
  int tx = threadIdx.x, ty = threadIdx.y;
#pragma unroll
  for (int yy = 0; yy < 4; ++yy) {
    int ff = f0 + tx;
    t[ty + yy * 8][tx] = (ff < 2049) ? src[(size_t)(b * 1024 + d0 + ty + yy * 8) * 2049 + ff] : (f16)0.f;
  }
  __syncthreads();
#pragma unroll
  for (int yy = 0; yy < 4; ++yy)
    dst[((size_t)b * 2176 + f0 + ty + yy * 8) * 1024 + d0 + tx] = t[tx][ty + yy * 8];
}

// ---------- energy GEMM: |Xf @ Wq| head-mean, fp16 MFMA, BM=128 BN=64 BK=64 ----------
__global__ __launch_bounds__(256) void k_energy(const f16* __restrict__ PReT, const f16* __restrict__ PImT,
                                                const f16* __restrict__ WqT, const float* __restrict__ bq,
                                                float* __restrict__ energy) {
  __shared__ __align__(16) f16 sAre[128 * 64];
  __shared__ __align__(16) f16 sAim[128 * 64];
  __shared__ __align__(16) f16 sBT[64 * 64];
  int tid = threadIdx.x;
  int lane = tid & 63, wv = tid >> 6;
  int bN = blockIdx.x;    // head
  int Mblk = blockIdx.y;  // 136 tiles of 128 rows over (b, f_pad)
  f32x4 accRe[2][4], accIm[2][4];
#pragma unroll
  for (int mf = 0; mf < 2; ++mf)
#pragma unroll
    for (int nf = 0; nf < 4; ++nf) { accRe[mf][nf] = 0; accIm[mf][nf] = 0; }

  const char* gAre0 = (const char*)PReT + (size_t)(Mblk * 128) * 2048;
  const char* gAim0 = (const char*)PImT + (size_t)(Mblk * 128) * 2048;
  const char* gB0 = (const char*)WqT + (size_t)(bN * 64) * 2048;
  int rb = wv * 32;

  for (int ks = 0; ks < 16; ++ks) {
    int kb = ks * 128;  // byte offset in row
#pragma unroll
    for (int it = 0; it < 4; ++it) {
      int bo_ = it * 4096 + tid * 16;
      int row = bo_ >> 7, cb = bo_ & 127;
      gl_lds16(gAre0 + (size_t)row * 2048 + kb + cb, (char*)sAre + it * 4096 + (tid >> 6) * 1024);
    }
#pragma unroll
    for (int it = 0; it < 4; ++it) {
      int bo_ = it * 4096 + tid * 16;
      int row = bo_ >> 7, cb = bo_ & 127;
      gl_lds16(gAim0 + (size_t)row * 2048 + kb + cb, (char*)sAim + it * 4096 + (tid >> 6) * 1024);
    }
#pragma unroll
    for (int it = 0; it < 2; ++it) {
      int bo_ = it * 4096 + tid * 16;
      int row = bo_ >> 7, cb = bo_ & 127;
      gl_lds16(gB0 + (size_t)row * 2048 + kb + cb, (char*)sBT + it * 4096 + (tid >> 6) * 1024);
    }
    __syncthreads();
#pragma unroll
    for (int kk = 0; kk < 64; kk += 32) {
      int ko = kk + ((lane >> 4) << 3);
      f16x8 aRe[2], aIm[2], bF[4];
#pragma unroll
      for (int mf = 0; mf < 2; ++mf) {
        aRe[mf] = *(const f16x8*)&sAre[(rb + mf * 16 + (lane & 15)) * 64 + ko];
        aIm[mf] = *(const f16x8*)&sAim[(rb + mf * 16 + (lane & 15)) * 64 + ko];
      }
#pragma unroll
      for (int nf = 0; nf < 4; ++nf)
        bF[nf] = *(const f16x8*)&sBT[(nf * 16 + (lane & 15)) * 64 + ko];
#pragma unroll
      for (int mf = 0; mf < 2; ++mf)
#pragma unroll
        for (int nf = 0; nf < 4; ++nf) {
          accRe[mf][nf] = __builtin_amdgcn_mfma_f32_16x16x32_f16(aRe[mf], bF[nf], accRe[mf][nf], 0, 0, 0);
          accIm[mf][nf] = __builtin_amdgcn_mfma_f32_16x16x32_f16(aIm[mf], bF[nf], accIm[mf][nf], 0, 0, 0);
        }
    }
    __syncthreads();
  }
  // epilogue: bias at f==0, |z|, mean over 64 head dims
#pragma unroll
  for (int mf = 0; mf < 2; ++mf) {
#pragma unroll
    for (int r = 0; r < 4; ++r) {
      int grow = Mblk * 128 + rb + mf * 16 + ((lane >> 4) << 2) + r;
      int bb = grow / 2176;
      int fp = grow - bb * 2176;
      float s = 0.f;
#pragma unroll
      for (int nf = 0; nf < 4; ++nf) {
        float re = accRe[mf][nf][r];
        float im = accIm[mf][nf][r];
        if (fp == 0) re += 4096.0f * bq[bN * 64 + nf * 16 + (lane & 15)];
        s += sqrtf(re * re + im * im);
      }
#pragma unroll
      for (int off = 1; off < 16; off <<= 1) s += __shfl_xor(s, off);
      if ((lane & 15) == 0)
        energy[((size_t)bb * 16 + bN) * 2176 + fp] = s * 0.015625f;
    }
  }
}

// ---------- top-64 per (b,h), descending, ties -> lower index ----------
__global__ __launch_bounds__(256) void k_topk(const float* __restrict__ energy, int* __restrict__ idxb) {
  __shared__ float vals[2049];
  __shared__ unsigned long long wbest[4];
  int tid = threadIdx.x, bh = blockIdx.x;
  const float* e = energy + (size_t)bh * 2176;
  for (int i = tid; i < 2049; i += 256) vals[i] = e[i];
  __syncthreads();
  for (int it = 0; it < 64; ++it) {
    unsigned long long best = 0ull;
    for (int f = tid; f < 2049; f += 256) {
      unsigned b32 = __float_as_uint(vals[f]);
      b32 = (b32 & 0x80000000u) ? ~b32 : (b32 | 0x80000000u);  // order-preserving
      unsigned long long k = ((unsigned long long)b32 << 12) | (unsigned)(4095 - f);
      best = (k > best) ? k : best;
    }
#pragma unroll
    for (int off = 32; off > 0; off >>= 1) {
      unsigned long long o = __shfl_xor(best, off);
      best = (o > best) ? o : best;
    }
    if ((tid & 63) == 0) wbest[tid >> 6] = best;
    __syncthreads();
    if (tid == 0) {
      unsigned long long b0 = wbest[0] > wbest[1] ? wbest[0] : wbest[1];
      unsigned long long b1 = wbest[2] > wbest[3] ? wbest[2] : wbest[3];
      unsigned long long bb = b0 > b1 ? b0 : b1;
      int f = 4095 - (int)(bb & 4095ull);
      idxb[bh * 64 + it] = f;
      vals[f] = -1.0f;
    }
    __syncthreads();
  }
}

// ---------- qkv GEMM: per (b,h), gathered Re rows @ [Wq|Wk|Wv] head slice ----------
// grid (bh=128, ksplit=4), 256 thr. M=64 bins, N=192 (q|k|v), K-chunk=256.
// A staged via global_load_lds with pre-swizzled source col (T2/m173): LDS linear,
// read with byte ^ ((row&7)<<4) -> conflict-free ds_read_b128.
__global__ __launch_bounds__(256) void k_qkv(const f16* __restrict__ PReT, const int* __restrict__ idxb,
                                             const f16* __restrict__ WqT, const f16* __restrict__ WkT,
                                             const f16* __restrict__ WvT, float* __restrict__ part) {
  __shared__ __align__(16) f16 sA[64 * 64];
  __shared__ __align__(16) f16 sB[192 * 64];
  __shared__ int fjs[64];
  int tid = threadIdx.x, lane = tid & 63, w = tid >> 6;
  int bh = blockIdx.x, ks = blockIdx.y;
  int b = bh >> 4, h = bh & 15;
  if (tid < 64) fjs[tid] = idxb[bh * 64 + tid];
  __syncthreads();
  f32x4 acc[4][3];
#pragma unroll
  for (int mf = 0; mf < 4; ++mf)
#pragma unroll
    for (int nf = 0; nf < 3; ++nf) acc[mf][nf] = 0;

  int l8 = lane & 7;   // 16B slot within 128B row
  int lr = lane >> 3;  // row within the 8-row chunk one gl_lds16 covers
  int swz = (l8 ^ lr) << 4;

  for (int kt = 0; kt < 4; ++kt) {
    int kbyte = ks * 512 + kt * 128;
#pragma unroll
    for (int t = 0; t < 2; ++t) {
      int ia = w * 2 + t;
      int row = ia * 8 + lr;
      const char* src = (const char*)PReT + (size_t)(b * 2176 + fjs[row]) * 2048 + kbyte + swz;
      gl_lds16(src, (char*)sA + ia * 1024);
    }
#pragma unroll
    for (int t = 0; t < 6; ++t) {
      int ib = w * 6 + t;
      int row = ib * 8 + lr;  // 0..191
      const f16* Wt = (row < 64) ? WqT : (row < 128) ? WkT : WvT;
      const char* src = (const char*)Wt + (size_t)(h * 64 + (row & 63)) * 2048 + kbyte + swz;
      gl_lds16(src, (char*)sB + ib * 1024);
    }
    __syncthreads();
#pragma unroll
    for (int kk = 0; kk < 64; kk += 32) {
      int cb = (kk << 1) + ((lane >> 4) << 4);
      int r = lane & 15;
      f16x8 aF[4], bF[3];
#pragma unroll
      for (int mf = 0; mf < 4; ++mf) {
        int row = mf * 16 + r;
        aF[mf] = *(const f16x8*)((const char*)sA + row * 128 + (cb ^ ((row & 7) << 4)));
      }
#pragma unroll
      for (int nf = 0; nf < 3; ++nf) {
        int row = w * 48 + nf * 16 + r;
        bF[nf] = *(const f16x8*)((const char*)sB + row * 128 + (cb ^ ((row & 7) << 4)));
      }
#pragma unroll
      for (int mf = 0; mf < 4; ++mf)
#pragma unroll
        for (int nf = 0; nf < 3; ++nf)
          acc[mf][nf] = __builtin_amdgcn_mfma_f32_16x16x32_f16(aF[mf], bF[nf], acc[mf][nf], 0, 0, 0);
    }
    __syncthreads();
  }
  // partials: part[ks][bh][m(64)][n(192)]
  float* pb = part + (size_t)(ks * 128 + bh) * 12288;
#pragma unroll
  for (int mf = 0; mf < 4; ++mf)
#pragma unroll
    for (int nf = 0; nf < 3; ++nf)
#pragma unroll
      for (int rr = 0; rr < 4; ++rr) {
        int m = mf * 16 + ((lane >> 4) << 2) + rr;
        int n = w * 48 + nf * 16 + (lane & 15);
        pb[m * 192 + n] = acc[mf][nf][rr];
      }
}

// ---------- reduce partials, bias at DC bin, scores, softmax, amp ----------
__global__ __launch_bounds__(256) void k_attn2(const float* __restrict__ part, const int* __restrict__ idxb,
                                               const float* __restrict__ bq, const float* __restrict__ bk,
                                               const float* __restrict__ bv, const float* __restrict__ Cre,
                                               float* __restrict__ amp) {
  __shared__ float sQKV[64][196];  // stride 196: 16B-aligned rows, banks spread
  __shared__ float scores[64], attns[64];
  __shared__ int fjs[64];
  __shared__ int dcrow;
  int tid = threadIdx.x, bh = blockIdx.x;
  int b = bh >> 4, h = bh & 15;
  if (tid == 0) dcrow = -1;
  __syncthreads();
  if (tid < 64) {
    int f = idxb[bh * 64 + tid];
    fjs[tid] = f;
    if (f == 0) dcrow = tid;  // bins distinct -> at most one writer
  }
  __syncthreads();
  const float4* p0 = (const float4*)(part + (size_t)bh * 12288);
  const size_t s4 = (size_t)128 * 12288 / 4;
#pragma unroll
  for (int it = 0; it < 12; ++it) {
    int e = it * 256 + tid;  // 0..3071 float4s
    float4 v0 = p0[e], v1 = p0[e + s4], v2 = p0[e + 2 * s4], v3 = p0[e + 3 * s4];
    float4 v;
    v.x = v0.x + v1.x + v2.x + v3.x;
    v.y = v0.y + v1.y + v2.y + v3.y;
    v.z = v0.z + v1.z + v2.z + v3.z;
    v.w = v0.w + v1.w + v2.w + v3.w;
    int m = e / 48, n0 = (e % 48) * 4;
    *(float4*)&sQKV[m][n0] = v;
  }
  __syncthreads();
  if (dcrow >= 0 && tid < 192) {
    const float* bias = (tid < 64) ? bq : (tid < 128) ? bk : bv;
    sQKV[dcrow][tid] += 4096.0f * bias[h * 64 + (tid & 63)];
  }
  __syncthreads();
  {
    int j = tid >> 2, p = tid & 3;
    float s = 0.f;
#pragma unroll
    for (int c = 0; c < 16; ++c) {
      int cc = p * 16 + c;
      s = fmaf(sQKV[j][cc], sQKV[j][64 + cc], s);
    }
    s += __shfl_xor(s, 1);
    s += __shfl_xor(s, 2);
    if (p == 0) scores[j] = s * 0.125f;  // / (sqrt(64)+1e-8)
  }
  __syncthreads();
  if (tid < 64) {
    float s = scores[tid];
    float m = s;
#pragma unroll
    for (int off = 32; off > 0; off >>= 1) m = fmaxf(m, __shfl_xor(m, off));
    float ev = expf(s - m);
    float sm = ev;
#pragma unroll
    for (int off = 32; off > 0; off >>= 1) sm += __shfl_xor(sm, off);
    attns[tid] = ev / sm;
  }
  __syncthreads();
  {
    int j = tid >> 2, d0 = (tid & 3) * 16;
    float at = attns[j];
    int fj = fjs[j];
    float wj = (fj == 0 || fj == 2048) ? 0.5f : 1.0f;
    float* ao = amp + ((size_t)bh * 64 + j) * 64 + d0;
#pragma unroll
    for (int q4 = 0; q4 < 4; ++q4) {
      float4 c4 = *(const float4*)&Cre[b * 1024 + h * 64 + d0 + q4 * 4];
      float4 vv = *(const float4*)&sQKV[j][128 + d0 + q4 * 4];
      float4 av;
      av.x = wj * (at * vv.x - c4.x);
      av.y = wj * (at * vv.y - c4.y);
      av.z = wj * (at * vv.z - c4.z);
      av.w = wj * (at * vv.w - c4.w);
      *(float4*)&ao[q4 * 4] = av;
    }
  }
}

// ---------- sparse irfft: out_t = [t==0]Cre + (2/L)(sum_j amp_j cos + Cim*g(t)) ----------
__global__ __launch_bounds__(256) void k_ot(const float* __restrict__ amp, const int* __restrict__ idxb,
                                            const float* __restrict__ Cre, const float* __restrict__ Cim,
                                            f16* __restrict__ OT) {
  __shared__ __align__(16) float sAmp[64][64];
  __shared__ __align__(16) float sCre[64];
  __shared__ __align__(16) float sCim[64];
  __shared__ int fjs[64];
  int tid = threadIdx.x;
  int bh = blockIdx.x >> 4, tch = blockIdx.x & 15;
  int b = bh >> 4, h = bh & 15;
  for (int e = tid; e < 4096; e += 256) ((float*)sAmp)[e] = amp[(size_t)bh * 4096 + e];
  if (tid < 64) {
    sCre[tid] = Cre[b * 1024 + h * 64 + tid];
    sCim[tid] = Cim[b * 1024 + h * 64 + tid];
    fjs[tid] = idxb[bh * 64 + tid];
  }
  __syncthreads();
  int t = tch * 256 + tid;
  float4 acc[16];
#pragma unroll
  for (int d4 = 0; d4 < 16; ++d4) acc[d4] = make_float4(0.f, 0.f, 0.f, 0.f);
  float ssum = 0.f;
  for (int jj = 0; jj < 64; ++jj) {
    int r = (fjs[jj] * t) & 4095;  // exact angle reduction: (f*t) mod L
    float ang = (float)r * 0.00153398078788564123f;  // 2*pi/4096
    float sn, cs;
    __sincosf(ang, &sn, &cs);
    ssum += sn;
    const float4* arow = (const float4*)&sAmp[jj][0];
#pragma unroll
    for (int d4 = 0; d4 < 16; ++d4) {
      float4 a = arow[d4];
      acc[d4].x = fmaf(a.x, cs, acc[d4].x);
      acc[d4].y = fmaf(a.y, cs, acc[d4].y);
      acc[d4].z = fmaf(a.z, cs, acc[d4].z);
      acc[d4].w = fmaf(a.w, cs, acc[d4].w);
    }
  }
  float g = ssum;
  if (t & 1) {  // constant-spectrum irfft contributes -(2/L)Cim*cot(pi t/L) at odd t
    int tp = (t <= 2048) ? t : 4096 - t;
    float sg = (t <= 2048) ? 1.f : -1.f;
    float aa = (float)tp * (PI_F / 4096.0f);
    g -= sg * (cosf(aa) / sinf(aa));
  }
  const float s2L = 2.0f / 4096.0f;
  int isT0 = (t == 0);
  f16* o16 = OT + ((size_t)bh * 4096 + t) * 64;
#pragma unroll
  for (int d4 = 0; d4 < 16; ++d4) {
    float4 ci4 = *(const float4*)&sCim[d4 * 4];
    float4 cr4 = *(const float4*)&sCre[d4 * 4];
    acc[d4].x = s2L * (acc[d4].x + ci4.x * g) + (isT0 ? cr4.x : 0.f);
    acc[d4].y = s2L * (acc[d4].y + ci4.y * g) + (isT0 ? cr4.y : 0.f);
    acc[d4].z = s2L * (acc[d4].z + ci4.z * g) + (isT0 ? cr4.z : 0.f);
    acc[d4].w = s2L * (acc[d4].w + ci4.w * g) + (isT0 ? cr4.w : 0.f);
  }
#pragma unroll
  for (int p = 0; p < 8; ++p) {
    float4 a = acc[2 * p], bb = acc[2 * p + 1];
    f16x8 v;
    v[0] = (f16)a.x; v[1] = (f16)a.y; v[2] = (f16)a.z; v[3] = (f16)a.w;
    v[4] = (f16)bb.x; v[5] = (f16)bb.y; v[6] = (f16)bb.z; v[7] = (f16)bb.w;
    *(f16x8*)(o16 + p * 8) = v;
  }
}

// ---------- final GEMM: out = OT(B,H,L,d as (b t) x (h d)) @ Wo + bo ----------
__global__ __launch_bounds__(256) void k_final(const f16* __restrict__ OT, const f16* __restrict__ WoT,
                                               const float* __restrict__ bo, float* __restrict__ out) {
  __shared__ __align__(16) f16 sA[128 * 64];
  __shared__ __align__(16) f16 sB[128 * 64];
  int tid = threadIdx.x, lane = tid & 63, wv = tid >> 6;
  int bN = blockIdx.x, Mblk = blockIdx.y;
  int wr = wv >> 1, wc = wv & 1;
  f32x4 acc[4][4];
#pragma unroll
  for (int mf = 0; mf < 4; ++mf)
#pragma unroll
    for (int nf = 0; nf < 4; ++nf) acc[mf][nf] = 0;
  int b = Mblk >> 5, t0 = (Mblk & 31) * 128;
  const char* gB0 = (const char*)WoT + (size_t)(bN * 128) * 2048;
  for (int ks = 0; ks < 16; ++ks) {  // k-step = one head's 64 dims
    const char* gA = (const char*)OT + (size_t)((b * 16 + ks) * 4096 + t0) * 128;
#pragma unroll
    for (int it = 0; it < 4; ++it) {
      int bo_ = it * 4096 + tid * 16;
      gl_lds16(gA + bo_, (char*)sA + it * 4096 + (tid >> 6) * 1024);
    }
    int kb = ks * 128;
#pragma unroll
    for (int it = 0; it < 4; ++it) {
      int bo_ = it * 4096 + tid * 16;
      int row = bo_ >> 7, cb = bo_ & 127;
      gl_lds16(gB0 + (size_t)row * 2048 + kb + cb, (char*)sB + it * 4096 + (tid >> 6) * 1024);
    }
    __syncthreads();
#pragma unroll
    for (int kk = 0; kk < 64; kk += 32) {
      int ko = kk + ((lane >> 4) << 3);
      f16x8 aF[4], bF[4];
#pragma unroll
      for (int mf = 0; mf < 4; ++mf)
        aF[mf] = *(const f16x8*)&sA[(wr * 64 + mf * 16 + (lane & 15)) * 64 + ko];
#pragma unroll
      for (int nf = 0; nf < 4; ++nf)
        bF[nf] = *(const f16x8*)&sB[(wc * 64 + nf * 16 + (lane & 15)) * 64 + ko];
#pragma unroll
      for (int mf = 0; mf < 4; ++mf)
#pragma unroll
        for (int nf = 0; nf < 4; ++nf)
          acc[mf][nf] = __builtin_amdgcn_mfma_f32_16x16x32_f16(aF[mf], bF[nf], acc[mf][nf], 0, 0, 0);
    }
    __syncthreads();
  }
#pragma unroll
  for (int nf = 0; nf < 4; ++nf) {
    int gcol = bN * 128 + wc * 64 + nf * 16 + (lane & 15);
    float bcol = bo[gcol];
#pragma unroll
    for (int mf = 0; mf < 4; ++mf) {
#pragma unroll
      for (int r = 0; r < 4; ++r) {
        int grow = Mblk * 128 + wr * 64 + mf * 16 + ((lane >> 4) << 2) + r;
        out[(size_t)grow * 1024 + gcol] = acc[mf][nf][r] + bcol;
      }
    }
  }
}

extern "C" void kernel_launch(void* const* d_in, const int* in_sizes, int n_in,
                              void* d_out, int out_size, void* d_ws, size_t ws_size,
                              hipStream_t stream) {
  const float* X = (const float*)d_in[0];
  const float* Wq = (const float*)d_in[1];
  const float* bq = (const float*)d_in[2];
  const float* Wk = (const float*)d_in[3];
  const float* bk = (const float*)d_in[4];
  const float* Wv = (const float*)d_in[5];
  const float* bv = (const float*)d_in[6];
  const float* Wo = (const float*)d_in[7];
  const float* bo = (const float*)d_in[8];
  float* out = (float*)d_out;

  if (ws_size < 208928768ULL) return;  // workspace plan below needs ~209MB
  char* w = (char*)d_ws;
  // Region1 (0..134MB): Xt f32 (B,D,L); after FFT reused:
  //   [0..35.7M)  PReT   [35.7..71.3M) PImT
  //   [71.3M) WkT(2M) WvT(2M) part(24M)  -- written after k_fft only
  float* Xt = (float*)(w);
  f16* PReT = (f16*)(w);
  f16* PImT = (f16*)(w + 35651584);
  f16* WkT = (f16*)(w + 71303168);
  f16* WvT = (f16*)(w + 73400320);
  float* part = (float*)(w + 75497472);  // 4*128*64*192*4 = 24MB, ends < 134MB
  // Region2 (134..201MB): untransposed fp16 planes; after t2 reused for OT
  char* R2 = w + 134217728;
  f16* PReU = (f16*)(R2);
  f16* PImU = (f16*)(R2 + 33570816);
  f16* OT = (f16*)(R2);
  // Region3: small buffers
  char* R3 = R2 + 67141632;
  float* sumXf = (float*)(R3);
  float* Cre = (float*)(R3 + 65536);
  float* Cim = (float*)(R3 + 98304);
  float* energy = (float*)(R3 + 131072);
  int* idxb = (int*)(R3 + 1245184);
  float* amp = (float*)(R3 + 1277952);
  f16* WqT = (f16*)(R3 + 3375104);
  f16* WoT = (f16*)(R3 + 5472256);

  dim3 b32(32, 8);
  hipLaunchKernelGGL(k_prep, dim3(32, 32, 2), b32, 0, stream, Wq, Wo, WqT, WoT);
  hipLaunchKernelGGL(k_t1, dim3(128, 32, 8), b32, 0, stream, X, Xt);
  hipLaunchKernelGGL(k_fft, dim3(8192), dim3(256), 0, stream, Xt, PReU, PImU, sumXf);
  hipLaunchKernelGGL(k_prep2, dim3(32, 32, 2), b32, 0, stream, Wk, Wv, WkT, WvT);  // after k_fft: Xt dead
  hipLaunchKernelGGL(k_C, dim3(32), dim3(256), 0, stream, sumXf, Wq, bq, Cre, Cim);
  hipLaunchKernelGGL(k_t2, dim3(68, 32, 16), b32, 0, stream, PReU, PImU, PReT, PImT);
  hipLaunchKernelGGL(k_energy, dim3(16, 136), dim3(256), 0, stream, PReT, PImT, WqT, bq, energy);
  hipLaunchKernelGGL(k_topk, dim3(128), dim3(256), 0, stream, energy, idxb);
  hipLaunchKernelGGL(k_qkv, dim3(128, 4), dim3(256), 0, stream, PReT, idxb, WqT, WkT, WvT, part);
  hipLaunchKernelGGL(k_attn2, dim3(128), dim3(256), 0, stream, part, idxb, bq, bk, bv, Cre, amp);
  hipLaunchKernelGGL(k_ot, dim3(2048), dim3(256), 0, stream, amp, idxb, Cre, Cim, OT);
  hipLaunchKernelGGL(k_final, dim3(8, 256), dim3(256), 0, stream, OT, WoT, bo, out);
}

// Round 3
// 689.324 us; speedup vs baseline: 1.2188x; 1.0199x over previous
//
#include <hip/hip_runtime.h>
#include <math.h>
#include <stdint.h>

// FrequencyAttention: B=8, L=4096, D=1024, H=16, dh=64, F=2049 (pad 2176), k=64
// Strategy: rfft(X) once; all projections commute with FFT; energy top-k via
// fp16 MFMA GEMM; sparse per-head attention (MFMA, K-split); closed-form
// sparse irfft; out GEMM. GEMMs use T2 LDS swizzle + XCD-aware block remap.

typedef _Float16 f16;
typedef _Float16 f16x8 __attribute__((ext_vector_type(8)));
typedef float f32x4 __attribute__((ext_vector_type(4)));

#define PI_F 3.14159265358979323846f

__device__ __forceinline__ void gl_lds16(const void* g, void* l) {
  __builtin_amdgcn_global_load_lds((const __attribute__((address_space(1))) void*)g,
                                   (__attribute__((address_space(3))) void*)l, 16, 0, 0);
}

// ---------- prep: transpose Wq, Wo to fp16 [out][in] for MFMA B-operand ----------
__global__ __launch_bounds__(256) void k_prep(const float* __restrict__ Wq, const float* __restrict__ Wo,
                                              f16* __restrict__ WqT, f16* __restrict__ WoT) {
  __shared__ float t[32][33];
  const float* src = blockIdx.z ? Wo : Wq;
  f16* dst = blockIdx.z ? WoT : WqT;
  int c0 = blockIdx.x * 32, r0 = blockIdx.y * 32;
  int tx = threadIdx.x, ty = threadIdx.y;
#pragma unroll
  for (int yy = 0; yy < 4; ++yy)
    t[ty + yy * 8][tx] = src[(size_t)(r0 + ty + yy * 8) * 1024 + c0 + tx];
  __syncthreads();
#pragma unroll
  for (int yy = 0; yy < 4; ++yy)
    dst[(size_t)(c0 + ty + yy * 8) * 1024 + r0 + tx] = (f16)t[tx][ty + yy * 8];
}

// ---------- prep2: transpose Wk, Wv to fp16 (runs after k_fft; lives in region1 tail) ----------
__global__ __launch_bounds__(256) void k_prep2(const float* __restrict__ Wk, const float* __restrict__ Wv,
                                               f16* __restrict__ WkT, f16* __restrict__ WvT) {
  __shared__ float t[32][33];
  const float* src = blockIdx.z ? Wv : Wk;
  f16* dst = blockIdx.z ? WvT : WkT;
  int c0 = blockIdx.x * 32, r0 = blockIdx.y * 32;
  int tx = threadIdx.x, ty = threadIdx.y;
#pragma unroll
  for (int yy = 0; yy < 4; ++yy)
    t[ty + yy * 8][tx] = src[(size_t)(r0 + ty + yy * 8) * 1024 + c0 + tx];
  __syncthreads();
#pragma unroll
  for (int yy = 0; yy < 4; ++yy)
    dst[(size_t)(c0 + ty + yy * 8) * 1024 + r0 + tx] = (f16)t[tx][ty + yy * 8];
}

// ---------- transpose X (B,L,D) -> Xt (B,D,L) f32 ----------
__global__ __launch_bounds__(256) void k_t1(const float* __restrict__ X, float* __restrict__ Xt) {
  __shared__ float t[32][33];
  int b = blockIdx.z;
  int l0 = blockIdx.x * 32, d0 = blockIdx.y * 32;
  int tx = threadIdx.x, ty = threadIdx.y;
#pragma unroll
  for (int yy = 0; yy < 4; ++yy)
    t[ty + yy * 8][tx] = X[((size_t)b * 4096 + l0 + ty + yy * 8) * 1024 + d0 + tx];
  __syncthreads();
#pragma unroll
  for (int yy = 0; yy < 4; ++yy)
    Xt[((size_t)b * 1024 + d0 + ty + yy * 8) * 4096 + l0 + tx] = t[tx][ty + yy * 8];
}

// ---------- rfft(4096 real) per (b,dm) via 2048-pt complex Stockham + untangle ----------
__global__ __launch_bounds__(256) void k_fft(const float* __restrict__ Xt,
                                             f16* __restrict__ PReU, f16* __restrict__ PImU,
                                             float* __restrict__ sumXf) {
  __shared__ float ar[2048], ai[2048], br[2048], bi[2048];
  __shared__ float twr[1024], twi[1024];
  __shared__ float redr[256], redi[256];
  int tid = threadIdx.x;
  int blk = blockIdx.x;  // b*1024 + dm

  for (int k = tid; k < 1024; k += 256) {
    float ang = (float)k * (-6.28318530717958647692f / 2048.0f);
    twr[k] = cosf(ang);
    twi[k] = sinf(ang);  // e^{-2pi i k/2048}
  }
  const float4* src = (const float4*)(Xt + (size_t)blk * 4096);
#pragma unroll
  for (int r = 0; r < 4; ++r) {
    int i4 = r * 256 + tid;
    float4 v = src[i4];
    ar[2 * i4] = v.x; ai[2 * i4] = v.y;       // z[n] = x[2n] + i x[2n+1]
    ar[2 * i4 + 1] = v.z; ai[2 * i4 + 1] = v.w;
  }
  __syncthreads();
  float *cr = ar, *ci = ai, *nr = br, *ni = bi;
  for (int st = 0; st < 11; ++st) {
#pragma unroll
    for (int r = 0; r < 4; ++r) {
      int i = r * 256 + tid;           // butterfly index 0..1023
      int p = i >> st;
      int q = i & ((1 << st) - 1);
      float xr = cr[i], xi = ci[i];
      float yr = cr[i + 1024], yi = ci[i + 1024];
      float sr = xr - yr, si = xi - yi;
      int tix = p << st;               // p * (2048/ncur)
      float wr = twr[tix], wi = twi[tix];
      int o0 = q + (p << (st + 1));
      nr[o0] = xr + yr; ni[o0] = xi + yi;
      nr[o0 + (1 << st)] = sr * wr - si * wi;
      ni[o0 + (1 << st)] = sr * wi + si * wr;
    }
    __syncthreads();
    float* tp;
    tp = cr; cr = nr; nr = tp;
    tp = ci; ci = ni; ni = tp;
  }
  // untangle real FFT: X[f] = E + e^{-2pi i f/4096} * O, f = 0..2048
  float sumr = 0.f, sumi = 0.f;
  const float c2 = 6.28318530717958647692f / 4096.0f;
  size_t obase = (size_t)blk * 2049;
  for (int f = tid; f <= 2048; f += 256) {
    int fz = f & 2047, fm = (2048 - f) & 2047;
    float zr = cr[fz], zi = ci[fz], mr = cr[fm], mi = ci[fm];
    float Er = 0.5f * (zr + mr), Ei = 0.5f * (zi - mi);
    float Or = 0.5f * (zi + mi), Oi = -0.5f * (zr - mr);
    float a = c2 * (float)f;
    float wr = cosf(a), wi = -sinf(a);
    float Xr = Er + wr * Or - wi * Oi;
    float Xi = Ei + wr * Oi + wi * Or;
    PReU[obase + f] = (f16)Xr;
    PImU[obase + f] = (f16)Xi;
    sumr += Xr; sumi += Xi;
  }
  __syncthreads();
  redr[tid] = sumr; redi[tid] = sumi;
  __syncthreads();
  for (int s = 128; s > 0; s >>= 1) {
    if (tid < s) { redr[tid] += redr[tid + s]; redi[tid] += redi[tid + s]; }
    __syncthreads();
  }
  if (tid == 0) { sumXf[2 * blk] = redr[0]; sumXf[2 * blk + 1] = redi[0]; }
}

// ---------- C = mean_f(q_freq) = (sumXf @ Wq + L*bq) / F ----------
__global__ __launch_bounds__(256) void k_C(const float* __restrict__ sumXf, const float* __restrict__ Wq,
                                           const float* __restrict__ bq,
                                           float* __restrict__ Cre, float* __restrict__ Cim) {
  int b = blockIdx.x >> 2;
  int hd = ((blockIdx.x & 3) << 8) + threadIdx.x;
  float accr = 0.f, acci = 0.f;
  for (int dm = 0; dm < 1024; ++dm) {
    float w = Wq[(size_t)dm * 1024 + hd];
    accr += sumXf[2 * (b * 1024 + dm)] * w;
    acci += sumXf[2 * (b * 1024 + dm) + 1] * w;
  }
  Cre[b * 1024 + hd] = (accr + 4096.0f * bq[hd]) * (1.0f / 2049.0f);
  Cim[b * 1024 + hd] = acci * (1.0f / 2049.0f);
}

// ---------- transpose planes (B*D, 2049) -> (B, 2176, D) fp16, zero-pad ----------
__global__ __launch_bounds__(256) void k_t2(const f16* __restrict__ PReU, const f16* __restrict__ PImU,
                                            f16* __restrict__ PReT, f16* __restrict__ PImT) {
  __shared__ f16 t[32][33];
  int z = blockIdx.z;
  int b = z >> 1;
  const f16* src = (z & 1) ? PImU : PReU;
  f16* dst = (z & 1) ? PImT : PReT;
  int f0 = blockIdx.x * 32, d0 = blockIdx.y * 32;
  int tx = threadIdx.x, ty = threadIdx.y;
#pragma unroll
  for (int yy = 0; yy < 4; ++yy) {
    int ff = f0 + tx;
    t[ty + yy * 8][tx] = (ff < 2049) ? src[(size_t)(b * 1024 + d0 + ty + yy * 8) * 2049 + ff] : (f16)0.f;
  }
  __syncthreads();
#pragma unroll
  for (int yy = 0; yy < 4; ++yy)
    dst[((size_t)b * 2176 + f0 + ty + yy * 8) * 1024 + d0 + tx] = t[tx][ty + yy * 8];
}

// ---------- energy GEMM: |Xf @ Wq| head-mean, fp16 MFMA, BM=128 BN=128 BK=64 ----------
// T2 swizzle (pre-swizzled gl_lds source + XOR read) + XCD-aware block remap.
__global__ __launch_bounds__(256) void k_energy(const f16* __restrict__ PReT, const f16* __restrict__ PImT,
                                                const f16* __restrict__ WqT, const float* __restrict__ bq,
                                                float* __restrict__ energy) {
  __shared__ __align__(16) f16 sAre[128 * 64];
  __shared__ __align__(16) f16 sAim[128 * 64];
  __shared__ __align__(16) f16 sB[128 * 64];
  int tid = threadIdx.x;
  int lane = tid & 63, w = tid >> 6;
  // XCD remap: all 8 N-blocks of one Mblk share lin%8 -> same XCD L2
  int lin = blockIdx.x;
  int xq = lin & 7, rq = lin >> 3;
  int bN = rq & 7;                    // 8 col-blocks of 128 (2 heads each)
  int Mblk = ((rq >> 3) << 3) + xq;   // 136 = 17*8 row tiles
  f32x4 accRe[2][8], accIm[2][8];
#pragma unroll
  for (int mf = 0; mf < 2; ++mf)
#pragma unroll
    for (int nf = 0; nf < 8; ++nf) { accRe[mf][nf] = 0; accIm[mf][nf] = 0; }

  const char* gAre0 = (const char*)PReT + (size_t)(Mblk * 128) * 2048;
  const char* gAim0 = (const char*)PImT + (size_t)(Mblk * 128) * 2048;
  const char* gB0 = (const char*)WqT + (size_t)(bN * 128) * 2048;
  int swz = ((tid & 7) ^ ((tid >> 3) & 7)) << 4;  // pre-swizzled source 16B slot
  int rb = w * 32;
  int r = lane & 15;
  int cq = (lane >> 4) << 4;

  for (int ks = 0; ks < 16; ++ks) {
    int kb = ks * 128;  // byte offset in K
#pragma unroll
    for (int it = 0; it < 4; ++it) {
      int row = it * 32 + (tid >> 3);
      gl_lds16(gAre0 + (size_t)row * 2048 + kb + swz, (char*)sAre + it * 4096 + w * 1024);
    }
#pragma unroll
    for (int it = 0; it < 4; ++it) {
      int row = it * 32 + (tid >> 3);
      gl_lds16(gAim0 + (size_t)row * 2048 + kb + swz, (char*)sAim + it * 4096 + w * 1024);
    }
#pragma unroll
    for (int it = 0; it < 4; ++it) {
      int row = it * 32 + (tid >> 3);
      gl_lds16(gB0 + (size_t)row * 2048 + kb + swz, (char*)sB + it * 4096 + w * 1024);
    }
    __syncthreads();
#pragma unroll
    for (int kk = 0; kk < 64; kk += 32) {
      int cb = (kk << 1) + cq;
      f16x8 aRe[2], aIm[2], bF[8];
#pragma unroll
      for (int mf = 0; mf < 2; ++mf) {
        int row = rb + mf * 16 + r;
        aRe[mf] = *(const f16x8*)((const char*)sAre + row * 128 + (cb ^ ((row & 7) << 4)));
        aIm[mf] = *(const f16x8*)((const char*)sAim + row * 128 + (cb ^ ((row & 7) << 4)));
      }
#pragma unroll
      for (int nf = 0; nf < 8; ++nf) {
        int row = nf * 16 + r;
        bF[nf] = *(const f16x8*)((const char*)sB + row * 128 + (cb ^ ((row & 7) << 4)));
      }
#pragma unroll
      for (int mf = 0; mf < 2; ++mf)
#pragma unroll
        for (int nf = 0; nf < 8; ++nf) {
          accRe[mf][nf] = __builtin_amdgcn_mfma_f32_16x16x32_f16(aRe[mf], bF[nf], accRe[mf][nf], 0, 0, 0);
          accIm[mf][nf] = __builtin_amdgcn_mfma_f32_16x16x32_f16(aIm[mf], bF[nf], accIm[mf][nf], 0, 0, 0);
        }
    }
    __syncthreads();
  }
  // epilogue: bias at f==0, |z|, mean over 64 head dims (2 heads per block)
#pragma unroll
  for (int mf = 0; mf < 2; ++mf) {
#pragma unroll
    for (int rr = 0; rr < 4; ++rr) {
      int grow = Mblk * 128 + rb + mf * 16 + ((lane >> 4) << 2) + rr;
      int bb = grow / 2176;
      int fp = grow - bb * 2176;
      float s0 = 0.f, s1 = 0.f;
#pragma unroll
      for (int nf = 0; nf < 8; ++nf) {
        float re = accRe[mf][nf][rr];
        float im = accIm[mf][nf][rr];
        if (fp == 0) re += 4096.0f * bq[bN * 128 + nf * 16 + r];
        float mag = sqrtf(re * re + im * im);
        if (nf < 4) s0 += mag; else s1 += mag;
      }
#pragma unroll
      for (int off = 1; off < 16; off <<= 1) {
        s0 += __shfl_xor(s0, off);
        s1 += __shfl_xor(s1, off);
      }
      if (r == 0) {
        energy[((size_t)bb * 16 + 2 * bN) * 2176 + fp] = s0 * 0.015625f;
        energy[((size_t)bb * 16 + 2 * bN + 1) * 2176 + fp] = s1 * 0.015625f;
      }
    }
  }
}

// ---------- top-64 per (b,h), descending, ties -> lower index ----------
__global__ __launch_bounds__(256) void k_topk(const float* __restrict__ energy, int* __restrict__ idxb) {
  __shared__ float vals[2049];
  __shared__ unsigned long long wbest[4];
  int tid = threadIdx.x, bh = blockIdx.x;
  const float* e = energy + (size_t)bh * 2176;
  for (int i = tid; i < 2049; i += 256) vals[i] = e[i];
  __syncthreads();
  for (int it = 0; it < 64; ++it) {
    unsigned long long best = 0ull;
    for (int f = tid; f < 2049; f += 256) {
      unsigned b32 = __float_as_uint(vals[f]);
      b32 = (b32 & 0x80000000u) ? ~b32 : (b32 | 0x80000000u);  // order-preserving
      unsigned long long k = ((unsigned long long)b32 << 12) | (unsigned)(4095 - f);
      best = (k > best) ? k : best;
    }
#pragma unroll
    for (int off = 32; off > 0; off >>= 1) {
      unsigned long long o = __shfl_xor(best, off);
      best = (o > best) ? o : best;
    }
    if ((tid & 63) == 0) wbest[tid >> 6] = best;
    __syncthreads();
    if (tid == 0) {
      unsigned long long b0 = wbest[0] > wbest[1] ? wbest[0] : wbest[1];
      unsigned long long b1 = wbest[2] > wbest[3] ? wbest[2] : wbest[3];
      unsigned long long bb = b0 > b1 ? b0 : b1;
      int f = 4095 - (int)(bb & 4095ull);
      idxb[bh * 64 + it] = f;
      vals[f] = -1.0f;
    }
    __syncthreads();
  }
}

// ---------- qkv GEMM: per (b,h), gathered Re rows @ [Wq|Wk|Wv] head slice ----------
__global__ __launch_bounds__(256) void k_qkv(const f16* __restrict__ PReT, const int* __restrict__ idxb,
                                             const f16* __restrict__ WqT, const f16* __restrict__ WkT,
                                             const f16* __restrict__ WvT, float* __restrict__ part) {
  __shared__ __align__(16) f16 sA[64 * 64];
  __shared__ __align__(16) f16 sB[192 * 64];
  __shared__ int fjs[64];
  int tid = threadIdx.x, lane = tid & 63, w = tid >> 6;
  int bh = blockIdx.x, ks = blockIdx.y;
  int b = bh >> 4, h = bh & 15;
  if (tid < 64) fjs[tid] = idxb[bh * 64 + tid];
  __syncthreads();
  f32x4 acc[4][3];
#pragma unroll
  for (int mf = 0; mf < 4; ++mf)
#pragma unroll
    for (int nf = 0; nf < 3; ++nf) acc[mf][nf] = 0;

  int l8 = lane & 7;   // 16B slot within 128B row
  int lr = lane >> 3;  // row within the 8-row chunk one gl_lds16 covers
  int swz = (l8 ^ lr) << 4;

  for (int kt = 0; kt < 4; ++kt) {
    int kbyte = ks * 512 + kt * 128;
#pragma unroll
    for (int t = 0; t < 2; ++t) {
      int ia = w * 2 + t;
      int row = ia * 8 + lr;
      const char* src = (const char*)PReT + (size_t)(b * 2176 + fjs[row]) * 2048 + kbyte + swz;
      gl_lds16(src, (char*)sA + ia * 1024);
    }
#pragma unroll
    for (int t = 0; t < 6; ++t) {
      int ib = w * 6 + t;
      int row = ib * 8 + lr;  // 0..191
      const f16* Wt = (row < 64) ? WqT : (row < 128) ? WkT : WvT;
      const char* src = (const char*)Wt + (size_t)(h * 64 + (row & 63)) * 2048 + kbyte + swz;
      gl_lds16(src, (char*)sB + ib * 1024);
    }
    __syncthreads();
#pragma unroll
    for (int kk = 0; kk < 64; kk += 32) {
      int cb = (kk << 1) + ((lane >> 4) << 4);
      int r = lane & 15;
      f16x8 aF[4], bF[3];
#pragma unroll
      for (int mf = 0; mf < 4; ++mf) {
        int row = mf * 16 + r;
        aF[mf] = *(const f16x8*)((const char*)sA + row * 128 + (cb ^ ((row & 7) << 4)));
      }
#pragma unroll
      for (int nf = 0; nf < 3; ++nf) {
        int row = w * 48 + nf * 16 + r;
        bF[nf] = *(const f16x8*)((const char*)sB + row * 128 + (cb ^ ((row & 7) << 4)));
      }
#pragma unroll
      for (int mf = 0; mf < 4; ++mf)
#pragma unroll
        for (int nf = 0; nf < 3; ++nf)
          acc[mf][nf] = __builtin_amdgcn_mfma_f32_16x16x32_f16(aF[mf], bF[nf], acc[mf][nf], 0, 0, 0);
    }
    __syncthreads();
  }
  // partials: part[ks][bh][m(64)][n(192)]
  float* pb = part + (size_t)(ks * 128 + bh) * 12288;
#pragma unroll
  for (int mf = 0; mf < 4; ++mf)
#pragma unroll
    for (int nf = 0; nf < 3; ++nf)
#pragma unroll
      for (int rr = 0; rr < 4; ++rr) {
        int m = mf * 16 + ((lane >> 4) << 2) + rr;
        int n = w * 48 + nf * 16 + (lane & 15);
        pb[m * 192 + n] = acc[mf][nf][rr];
      }
}

// ---------- reduce partials, bias at DC bin, scores, softmax, amp ----------
__global__ __launch_bounds__(256) void k_attn2(const float* __restrict__ part, const int* __restrict__ idxb,
                                               const float* __restrict__ bq, const float* __restrict__ bk,
                                               const float* __restrict__ bv, const float* __restrict__ Cre,
                                               float* __restrict__ amp) {
  __shared__ float sQKV[64][196];  // stride 196: 16B-aligned rows, banks spread
  __shared__ float scores[64], attns[64];
  __shared__ int fjs[64];
  __shared__ int dcrow;
  int tid = threadIdx.x, bh = blockIdx.x;
  int b = bh >> 4, h = bh & 15;
  if (tid == 0) dcrow = -1;
  __syncthreads();
  if (tid < 64) {
    int f = idxb[bh * 64 + tid];
    fjs[tid] = f;
    if (f == 0) dcrow = tid;  // bins distinct -> at most one writer
  }
  __syncthreads();
  const float4* p0 = (const float4*)(part + (size_t)bh * 12288);
  const size_t s4 = (size_t)128 * 12288 / 4;
#pragma unroll
  for (int it = 0; it < 12; ++it) {
    int e = it * 256 + tid;  // 0..3071 float4s
    float4 v0 = p0[e], v1 = p0[e + s4], v2 = p0[e + 2 * s4], v3 = p0[e + 3 * s4];
    float4 v;
    v.x = v0.x + v1.x + v2.x + v3.x;
    v.y = v0.y + v1.y + v2.y + v3.y;
    v.z = v0.z + v1.z + v2.z + v3.z;
    v.w = v0.w + v1.w + v2.w + v3.w;
    int m = e / 48, n0 = (e % 48) * 4;
    *(float4*)&sQKV[m][n0] = v;
  }
  __syncthreads();
  if (dcrow >= 0 && tid < 192) {
    const float* bias = (tid < 64) ? bq : (tid < 128) ? bk : bv;
    sQKV[dcrow][tid] += 4096.0f * bias[h * 64 + (tid & 63)];
  }
  __syncthreads();
  {
    int j = tid >> 2, p = tid & 3;
    float s = 0.f;
#pragma unroll
    for (int c = 0; c < 16; ++c) {
      int cc = p * 16 + c;
      s = fmaf(sQKV[j][cc], sQKV[j][64 + cc], s);
    }
    s += __shfl_xor(s, 1);
    s += __shfl_xor(s, 2);
    if (p == 0) scores[j] = s * 0.125f;  // / (sqrt(64)+1e-8)
  }
  __syncthreads();
  if (tid < 64) {
    float s = scores[tid];
    float m = s;
#pragma unroll
    for (int off = 32; off > 0; off >>= 1) m = fmaxf(m, __shfl_xor(m, off));
    float ev = expf(s - m);
    float sm = ev;
#pragma unroll
    for (int off = 32; off > 0; off >>= 1) sm += __shfl_xor(sm, off);
    attns[tid] = ev / sm;
  }
  __syncthreads();
  {
    int j = tid >> 2, d0 = (tid & 3) * 16;
    float at = attns[j];
    int fj = fjs[j];
    float wj = (fj == 0 || fj == 2048) ? 0.5f : 1.0f;
    float* ao = amp + ((size_t)bh * 64 + j) * 64 + d0;
#pragma unroll
    for (int q4 = 0; q4 < 4; ++q4) {
      float4 c4 = *(const float4*)&Cre[b * 1024 + h * 64 + d0 + q4 * 4];
      float4 vv = *(const float4*)&sQKV[j][128 + d0 + q4 * 4];
      float4 av;
      av.x = wj * (at * vv.x - c4.x);
      av.y = wj * (at * vv.y - c4.y);
      av.z = wj * (at * vv.z - c4.z);
      av.w = wj * (at * vv.w - c4.w);
      *(float4*)&ao[q4 * 4] = av;
    }
  }
}

// ---------- sparse irfft: out_t = [t==0]Cre + (2/L)(sum_j amp_j cos + Cim*g(t)) ----------
__global__ __launch_bounds__(256) void k_ot(const float* __restrict__ amp, const int* __restrict__ idxb,
                                            const float* __restrict__ Cre, const float* __restrict__ Cim,
                                            f16* __restrict__ OT) {
  __shared__ __align__(16) float sAmp[64][64];
  __shared__ __align__(16) float sCre[64];
  __shared__ __align__(16) float sCim[64];
  __shared__ int fjs[64];
  int tid = threadIdx.x;
  int bh = blockIdx.x >> 4, tch = blockIdx.x & 15;
  int b = bh >> 4, h = bh & 15;
  for (int e = tid; e < 4096; e += 256) ((float*)sAmp)[e] = amp[(size_t)bh * 4096 + e];
  if (tid < 64) {
    sCre[tid] = Cre[b * 1024 + h * 64 + tid];
    sCim[tid] = Cim[b * 1024 + h * 64 + tid];
    fjs[tid] = idxb[bh * 64 + tid];
  }
  __syncthreads();
  int t = tch * 256 + tid;
  float4 acc[16];
#pragma unroll
  for (int d4 = 0; d4 < 16; ++d4) acc[d4] = make_float4(0.f, 0.f, 0.f, 0.f);
  float ssum = 0.f;
  for (int jj = 0; jj < 64; ++jj) {
    int r = (fjs[jj] * t) & 4095;  // exact angle reduction: (f*t) mod L
    float ang = (float)r * 0.00153398078788564123f;  // 2*pi/4096
    float sn, cs;
    __sincosf(ang, &sn, &cs);
    ssum += sn;
    const float4* arow = (const float4*)&sAmp[jj][0];
#pragma unroll
    for (int d4 = 0; d4 < 16; ++d4) {
      float4 a = arow[d4];
      acc[d4].x = fmaf(a.x, cs, acc[d4].x);
      acc[d4].y = fmaf(a.y, cs, acc[d4].y);
      acc[d4].z = fmaf(a.z, cs, acc[d4].z);
      acc[d4].w = fmaf(a.w, cs, acc[d4].w);
    }
  }
  float g = ssum;
  if (t & 1) {  // constant-spectrum irfft contributes -(2/L)Cim*cot(pi t/L) at odd t
    int tp = (t <= 2048) ? t : 4096 - t;
    float sg = (t <= 2048) ? 1.f : -1.f;
    float aa = (float)tp * (PI_F / 4096.0f);
    g -= sg * (cosf(aa) / sinf(aa));
  }
  const float s2L = 2.0f / 4096.0f;
  int isT0 = (t == 0);
  f16* o16 = OT + ((size_t)bh * 4096 + t) * 64;
#pragma unroll
  for (int d4 = 0; d4 < 16; ++d4) {
    float4 ci4 = *(const float4*)&sCim[d4 * 4];
    float4 cr4 = *(const float4*)&sCre[d4 * 4];
    acc[d4].x = s2L * (acc[d4].x + ci4.x * g) + (isT0 ? cr4.x : 0.f);
    acc[d4].y = s2L * (acc[d4].y + ci4.y * g) + (isT0 ? cr4.y : 0.f);
    acc[d4].z = s2L * (acc[d4].z + ci4.z * g) + (isT0 ? cr4.z : 0.f);
    acc[d4].w = s2L * (acc[d4].w + ci4.w * g) + (isT0 ? cr4.w : 0.f);
  }
#pragma unroll
  for (int p = 0; p < 8; ++p) {
    float4 a = acc[2 * p], bb = acc[2 * p + 1];
    f16x8 v;
    v[0] = (f16)a.x; v[1] = (f16)a.y; v[2] = (f16)a.z; v[3] = (f16)a.w;
    v[4] = (f16)bb.x; v[5] = (f16)bb.y; v[6] = (f16)bb.z; v[7] = (f16)bb.w;
    *(f16x8*)(o16 + p * 8) = v;
  }
}

// ---------- final GEMM: out = OT(B,H,L,d as (b t) x (h d)) @ Wo + bo ----------
// T2 swizzle + XCD-aware remap (256 Mblk = 32*8).
__global__ __launch_bounds__(256) void k_final(const f16* __restrict__ OT, const f16* __restrict__ WoT,
                                               const float* __restrict__ bo, float* __restrict__ out) {
  __shared__ __align__(16) f16 sA[128 * 64];
  __shared__ __align__(16) f16 sB[128 * 64];
  int tid = threadIdx.x, lane = tid & 63, wv = tid >> 6;
  int lin = blockIdx.x;
  int xq = lin & 7, rq = lin >> 3;
  int bN = rq & 7;
  int Mblk = ((rq >> 3) << 3) + xq;  // 256 = 32*8
  int wr = wv >> 1, wc = wv & 1;
  f32x4 acc[4][4];
#pragma unroll
  for (int mf = 0; mf < 4; ++mf)
#pragma unroll
    for (int nf = 0; nf < 4; ++nf) acc[mf][nf] = 0;
  int b = Mblk >> 5, t0 = (Mblk & 31) * 128;
  const char* gB0 = (const char*)WoT + (size_t)(bN * 128) * 2048;
  int swz = ((tid & 7) ^ ((tid >> 3) & 7)) << 4;
  int r = lane & 15;
  int cq = (lane >> 4) << 4;
  for (int ks = 0; ks < 16; ++ks) {  // k-step = one head's 64 dims
    const char* gA = (const char*)OT + (size_t)((b * 16 + ks) * 4096 + t0) * 128;
#pragma unroll
    for (int it = 0; it < 4; ++it) {
      int row = it * 32 + (tid >> 3);
      gl_lds16(gA + (size_t)row * 128 + swz, (char*)sA + it * 4096 + wv * 1024);
    }
    int kb = ks * 128;
#pragma unroll
    for (int it = 0; it < 4; ++it) {
      int row = it * 32 + (tid >> 3);
      gl_lds16(gB0 + (size_t)row * 2048 + kb + swz, (char*)sB + it * 4096 + wv * 1024);
    }
    __syncthreads();
#pragma unroll
    for (int kk = 0; kk < 64; kk += 32) {
      int cb = (kk << 1) + cq;
      f16x8 aF[4], bF[4];
#pragma unroll
      for (int mf = 0; mf < 4; ++mf) {
        int row = wr * 64 + mf * 16 + r;
        aF[mf] = *(const f16x8*)((const char*)sA + row * 128 + (cb ^ ((row & 7) << 4)));
      }
#pragma unroll
      for (int nf = 0; nf < 4; ++nf) {
        int row = wc * 64 + nf * 16 + r;
        bF[nf] = *(const f16x8*)((const char*)sB + row * 128 + (cb ^ ((row & 7) << 4)));
      }
#pragma unroll
      for (int mf = 0; mf < 4; ++mf)
#pragma unroll
        for (int nf = 0; nf < 4; ++nf)
          acc[mf][nf] = __builtin_amdgcn_mfma_f32_16x16x32_f16(aF[mf], bF[nf], acc[mf][nf], 0, 0, 0);
    }
    __syncthreads();
  }
#pragma unroll
  for (int nf = 0; nf < 4; ++nf) {
    int gcol = bN * 128 + wc * 64 + nf * 16 + (lane & 15);
    float bcol = bo[gcol];
#pragma unroll
    for (int mf = 0; mf < 4; ++mf) {
#pragma unroll
      for (int rr = 0; rr < 4; ++rr) {
        int grow = Mblk * 128 + wr * 64 + mf * 16 + ((lane >> 4) << 2) + rr;
        out[(size_t)grow * 1024 + gcol] = acc[mf][nf][rr] + bcol;
      }
    }
  }
}

extern "C" void kernel_launch(void* const* d_in, const int* in_sizes, int n_in,
                              void* d_out, int out_size, void* d_ws, size_t ws_size,
                              hipStream_t stream) {
  const float* X = (const float*)d_in[0];
  const float* Wq = (const float*)d_in[1];
  const float* bq = (const float*)d_in[2];
  const float* Wk = (const float*)d_in[3];
  const float* bk = (const float*)d_in[4];
  const float* Wv = (const float*)d_in[5];
  const float* bv = (const float*)d_in[6];
  const float* Wo = (const float*)d_in[7];
  const float* bo = (const float*)d_in[8];
  float* out = (float*)d_out;

  if (ws_size < 208928768ULL) return;  // workspace plan below needs ~209MB
  char* w = (char*)d_ws;
  // Region1 (0..134MB): Xt f32 (B,D,L); after FFT reused:
  //   [0..35.7M)  PReT   [35.7..71.3M) PImT
  //   [71.3M) WkT(2M) WvT(2M) part(24M)  -- written after k_fft only
  float* Xt = (float*)(w);
  f16* PReT = (f16*)(w);
  f16* PImT = (f16*)(w + 35651584);
  f16* WkT = (f16*)(w + 71303168);
  f16* WvT = (f16*)(w + 73400320);
  float* part = (float*)(w + 75497472);  // 4*128*64*192*4 = 24MB, ends < 134MB
  // Region2 (134..201MB): untransposed fp16 planes; after t2 reused for OT
  char* R2 = w + 134217728;
  f16* PReU = (f16*)(R2);
  f16* PImU = (f16*)(R2 + 33570816);
  f16* OT = (f16*)(R2);
  // Region3: small buffers
  char* R3 = R2 + 67141632;
  float* sumXf = (float*)(R3);
  float* Cre = (float*)(R3 + 65536);
  float* Cim = (float*)(R3 + 98304);
  float* energy = (float*)(R3 + 131072);
  int* idxb = (int*)(R3 + 1245184);
  float* amp = (float*)(R3 + 1277952);
  f16* WqT = (f16*)(R3 + 3375104);
  f16* WoT = (f16*)(R3 + 5472256);

  dim3 b32(32, 8);
  hipLaunchKernelGGL(k_prep, dim3(32, 32, 2), b32, 0, stream, Wq, Wo, WqT, WoT);
  hipLaunchKernelGGL(k_t1, dim3(128, 32, 8), b32, 0, stream, X, Xt);
  hipLaunchKernelGGL(k_fft, dim3(8192), dim3(256), 0, stream, Xt, PReU, PImU, sumXf);
  hipLaunchKernelGGL(k_prep2, dim3(32, 32, 2), b32, 0, stream, Wk, Wv, WkT, WvT);  // after k_fft: Xt dead
  hipLaunchKernelGGL(k_C, dim3(32), dim3(256), 0, stream, sumXf, Wq, bq, Cre, Cim);
  hipLaunchKernelGGL(k_t2, dim3(68, 32, 16), b32, 0, stream, PReU, PImU, PReT, PImT);
  hipLaunchKernelGGL(k_energy, dim3(1088), dim3(256), 0, stream, PReT, PImT, WqT, bq, energy);
  hipLaunchKernelGGL(k_topk, dim3(128), dim3(256), 0, stream, energy, idxb);
  hipLaunchKernelGGL(k_qkv, dim3(128, 4), dim3(256), 0, stream, PReT, idxb, WqT, WkT, WvT, part);
  hipLaunchKernelGGL(k_attn2, dim3(128), dim3(256), 0, stream, part, idxb, bq, bk, bv, Cre, amp);
  hipLaunchKernelGGL(k_ot, dim3(2048), dim3(256), 0, stream, amp, idxb, Cre, Cim, OT);
  hipLaunchKernelGGL(k_final, dim3(2048), dim3(256), 0, stream, OT, WoT, bo, out);
}